// Round 10
// baseline (604.700 us; speedup 1.0000x reference)
//
#include <hip/hip_runtime.h>
#include <cstdint>
#include <cstddef>

// Problem shape (fixed by the reference): B=8, C=192, Tx=512, Ty=2048.
#define BB 8
#define CC 192
#define TXX 512
#define TYY 2048

#define NEG_INF (-1e9f)
#define HALF_LOG_2PI 0.9189385332046727f  // 0.5*log(2*pi)

// ---- output layout (floats, concatenated in return order) ----
#define O1 8388608
#define O2 11534336
#define O3 14680064
#define O4 14680065

// ---- workspace layout (bytes) ----
#define WS_NEG   0           // neg_cent fp32 [B,Ty,Tx]           33,554,432 B
#define WS_S     33554432    // s_p_sq_r [B,C,Tx]                  3,145,728 B
#define WS_MSR   36700160    // m_p * s  [B,C,Tx]                  3,145,728 B
#define WS_BIAS  39845888    // nc1+nc4  [B,Tx]                       16,384 B
#define WS_DIRS  39862272    // dir bits [B,Ty/4,64] dwords        1,048,576 B
#define WS_IDX   40910848    // idx_map  [B,Ty] int                   65,536 B
#define WS_LENS  40976384    // int text_len[8], spec_len[8]             64 B
#define WS_PART  40976448    // kl partials [3072] float              12,288 B

typedef float f32x4 __attribute__((ext_vector_type(4)));

// ---------------------------------------------------------------------------
__global__ void k_zero(float* __restrict__ out) {
    int64_t i = (int64_t)blockIdx.x * blockDim.x + threadIdx.x;
    const int64_t n4 = (int64_t)BB * TYY * TXX / 4;
    float4 z4 = make_float4(0.f, 0.f, 0.f, 0.f);
    float4* p4 = (float4*)out;
    for (int64_t k = i; k < n4; k += (int64_t)gridDim.x * blockDim.x) p4[k] = z4;
    if (i < BB * TXX) out[O4 + i] = 0.0f;
}

__global__ void k_prep(const float* __restrict__ logs_p, const float* __restrict__ m_p,
                       float* __restrict__ s, float* __restrict__ msr) {
    int i = blockIdx.x * blockDim.x + threadIdx.x;
    float lp = logs_p[i], m = m_p[i];
    float sv = expf(-2.0f * lp);
    s[i] = sv;
    msr[i] = m * sv;
}

// 64 blocks x 64 threads -> 64 CUs active.
__global__ void k_bias(const float* __restrict__ logs_p, const float* __restrict__ m_p,
                       const float* __restrict__ msr, float* __restrict__ bias) {
    int i = blockIdx.x * blockDim.x + threadIdx.x;  // B*Tx = 4096 threads
    int b = i >> 9, x = i & (TXX - 1);
    size_t base = (size_t)b * CC * TXX + x;
    const float* lpb = logs_p + base;
    const float* mb  = m_p + base;
    const float* msb = msr + base;
    float acc = 0.f;
#pragma unroll 8
    for (int c = 0; c < CC; ++c)
        acc += -HALF_LOG_2PI - lpb[(size_t)c * TXX] - 0.5f * mb[(size_t)c * TXX] * msb[(size_t)c * TXX];
    bias[i] = acc;
}

__global__ void k_len(const float* __restrict__ tmask, const float* __restrict__ smask,
                      int* __restrict__ lens) {
    __shared__ float red[256];
    int b = blockIdx.x, tid = threadIdx.x;
    float ts = 0.f;
    for (int i = tid; i < TXX; i += 256) ts += tmask[b * TXX + i];
    red[tid] = ts; __syncthreads();
    for (int s = 128; s > 0; s >>= 1) { if (tid < s) red[tid] += red[tid + s]; __syncthreads(); }
    if (tid == 0) lens[b] = (int)(red[0] + 0.5f);
    __syncthreads();
    float ss = 0.f;
    for (int i = tid; i < TYY; i += 256) ss += smask[b * TYY + i];
    red[tid] = ss; __syncthreads();
    for (int s = 128; s > 0; s >>= 1) { if (tid < s) red[tid] += red[tid + s]; __syncthreads(); }
    if (tid == 0) lens[8 + b] = (int)(red[0] + 0.5f);
}

// ---------------------------------------------------------------------------
// neg_cent GEMM v2 (R24): 64(x) x 128(t) tile, 4x8 acc/thread, BK=16.
// R23 analysis: old 64x64/4x4 tile = 3 ds_read_b128 per 32 FLOP (10.7
// FLOP/read), LDS/issue-bound at ~4-6x above the 157TF fp32 roofline
// (k_gemm inferred ~200-250us of the 360us non-k_fwd time). New tile:
// 4 ds_read_b128 per 64 FLOP (16 FLOP/read). Accumulation order per output
// is UNCHANGED (k0 asc, k asc, fma(a,bm,acc) then fma(a2,bs,acc)) ->
// bitwise-identical neg_cent. Mask granularity on t coarsens 64->128
// (<=6% extra masked work; correctness per R14 note unchanged).
// ---------------------------------------------------------------------------
__global__ __launch_bounds__(256) void k_gemm(const float* __restrict__ z,
                                              const float* __restrict__ msr,
                                              const float* __restrict__ sarr,
                                              const float* __restrict__ bias,
                                              const int* __restrict__ lens,
                                              float* __restrict__ neg) {
    int x0 = blockIdx.x * 64, t0 = blockIdx.y * 128, b = blockIdx.z;
    if (x0 >= lens[b] || t0 >= lens[8 + b]) return;   // masked tile

    __shared__ float Zs[16][132];            // [k][t] +4 pad
    __shared__ float Ms[16][68], Ss[16][68]; // [k][x] +4 pad
    int tid = threadIdx.x;
    int tx = tid & 15, ty = tid >> 4;        // tx: x/4, ty: t/8
    const float* zb = z    + (size_t)b * CC * TYY;
    const float* mb = msr  + (size_t)b * CC * TXX;
    const float* sb = sarr + (size_t)b * CC * TXX;
    // staging indices: Z has 512 float4 (row=q>>5 of 16, col4=q&31 of 32)
    int zr0 = tid >> 5, zc0 = (tid & 31) * 4;          // q = tid
    int zr1 = (tid + 256) >> 5, zc1 = zc0;             // q = tid+256
    int mr = tid >> 4, mc = (tid & 15) * 4;
    float acc[8][4] = {};
    for (int k0 = 0; k0 < CC; k0 += 16) {
        float4 zv0 = *(const float4*)(zb + (size_t)(k0 + zr0) * TYY + t0 + zc0);
        float4 zv1 = *(const float4*)(zb + (size_t)(k0 + zr1) * TYY + t0 + zc1);
        float4 mv  = *(const float4*)(mb + (size_t)(k0 + mr) * TXX + x0 + mc);
        float4 sv  = *(const float4*)(sb + (size_t)(k0 + mr) * TXX + x0 + mc);
        __syncthreads();
        *(float4*)&Zs[zr0][zc0] = zv0;
        *(float4*)&Zs[zr1][zc1] = zv1;
        *(float4*)&Ms[mr][mc] = mv;
        *(float4*)&Ss[mr][mc] = sv;
        __syncthreads();
#pragma unroll
        for (int k = 0; k < 16; ++k) {
            float4 za = *(const float4*)&Zs[k][ty * 8];
            float4 zb4 = *(const float4*)&Zs[k][ty * 8 + 4];
            float4 bm4 = *(const float4*)&Ms[k][tx * 4];
            float4 bs4 = *(const float4*)&Ss[k][tx * 4];
            float zt[8] = {za.x, za.y, za.z, za.w, zb4.x, zb4.y, zb4.z, zb4.w};
            float bmv[4] = {bm4.x, bm4.y, bm4.z, bm4.w};
            float bsv[4] = {bs4.x, bs4.y, bs4.z, bs4.w};
#pragma unroll
            for (int i2 = 0; i2 < 8; ++i2) {
                float a = zt[i2];
                float a2 = -0.5f * a * a;
#pragma unroll
                for (int j = 0; j < 4; ++j)
                    acc[i2][j] += a * bmv[j] + a2 * bsv[j];
            }
        }
    }
    float4 b4 = *(const float4*)(bias + b * TXX + x0 + tx * 4);
    float bv[4] = {b4.x, b4.y, b4.z, b4.w};
#pragma unroll
    for (int i2 = 0; i2 < 8; ++i2) {
        int t = t0 + ty * 8 + i2;
        float4 o;
        o.x = acc[i2][0] + bv[0]; o.y = acc[i2][1] + bv[1];
        o.z = acc[i2][2] + bv[2]; o.w = acc[i2][3] + bv[3];
        *(float4*)(neg + ((size_t)b * TYY + t) * TXX + x0 + tx * 4) = o;
    }
}

// ---------------------------------------------------------------------------
// MAS forward pass v5 (R24: byte-exact revert to the best-measured config,
// 203us; R22/R23's no-spill variants regressed -- hipcc spills large
// cross-iteration asm register tiles regardless of theoretical fit).
// One wave per batch, asm-pinned 3-buffer 8-row prefetch, counted vmcnt.
// ---------------------------------------------------------------------------
#define GLOAD4(DST, PTR, OFF)                                             \
    asm volatile("global_load_dwordx4 %0, %1, off offset:" #OFF           \
                 : "=v"(DST) : "v"(PTR) : "memory")

#define WAIT_VM(N) do {                                                   \
    asm volatile("s_waitcnt vmcnt(" #N ")" ::: "memory");                 \
    __builtin_amdgcn_sched_barrier(0);                                    \
} while (0)

// 8 rows x 512 floats; lane owns 32B (two float4) per row. 4 base pointers
// (rows {0,1},{2,3},{4,5},{6,7}), imm offsets {0,16,2048,2064}.
#define LOADG(DST, G) do {                                                \
    const char* p0_ = (const char*)nc4 + (size_t)(G) * 16384 + lane * 32; \
    const char* p2_ = p0_ + 4096;                                         \
    const char* p4_ = p0_ + 8192;                                         \
    const char* p6_ = p0_ + 12288;                                        \
    GLOAD4(DST[0],  p0_, 0);    GLOAD4(DST[1],  p0_, 16);                 \
    GLOAD4(DST[2],  p0_, 2048); GLOAD4(DST[3],  p0_, 2064);               \
    GLOAD4(DST[4],  p2_, 0);    GLOAD4(DST[5],  p2_, 16);                 \
    GLOAD4(DST[6],  p2_, 2048); GLOAD4(DST[7],  p2_, 2064);               \
    GLOAD4(DST[8],  p4_, 0);    GLOAD4(DST[9],  p4_, 16);                 \
    GLOAD4(DST[10], p4_, 2048); GLOAD4(DST[11], p4_, 2064);               \
    GLOAD4(DST[12], p6_, 0);    GLOAD4(DST[13], p6_, 16);                 \
    GLOAD4(DST[14], p6_, 2048); GLOAD4(DST[15], p6_, 2064);               \
} while (0)

#define DPROW(CUR, YB, R) do {                                                \
    int y_ = (YB) + (R);                                                      \
    float s0_ = CUR[2*(R)][0],   s1_ = CUR[2*(R)][1];                         \
    float s2_ = CUR[2*(R)][2],   s3_ = CUR[2*(R)][3];                         \
    float s4_ = CUR[2*(R)+1][0], s5_ = CUR[2*(R)+1][1];                       \
    float s6_ = CUR[2*(R)+1][2], s7_ = CUR[2*(R)+1][3];                       \
    unsigned d_ = 0;                                                          \
    if (y_ == 0) {                                                            \
        if (lane == 0) v[0] = s0_;   /* only x==0 scored on row 0 */          \
    } else {                                                                  \
        float pl_ = __int_as_float(__builtin_amdgcn_update_dpp(               \
            0, __float_as_int(v[7]), 0x138, 0xF, 0xF, false));                \
        if (lane == 0) pl_ = NEG_INF;                                         \
        float n0_ = s0_ + fmaxf(v[0], pl_);  if (pl_  > v[0]) d_ |= 1u;       \
        float n1_ = s1_ + fmaxf(v[1], v[0]); if (v[0] > v[1]) d_ |= 2u;       \
        float n2_ = s2_ + fmaxf(v[2], v[1]); if (v[1] > v[2]) d_ |= 4u;       \
        float n3_ = s3_ + fmaxf(v[3], v[2]); if (v[2] > v[3]) d_ |= 8u;       \
        float n4_ = s4_ + fmaxf(v[4], v[3]); if (v[3] > v[4]) d_ |= 16u;      \
        float n5_ = s5_ + fmaxf(v[5], v[4]); if (v[4] > v[5]) d_ |= 32u;      \
        float n6_ = s6_ + fmaxf(v[6], v[5]); if (v[5] > v[6]) d_ |= 64u;      \
        float n7_ = s7_ + fmaxf(v[7], v[6]); if (v[6] > v[7]) d_ |= 128u;     \
        v[0] = n0_; v[1] = n1_; v[2] = n2_; v[3] = n3_;                       \
        v[4] = n4_; v[5] = n5_; v[6] = n6_; v[7] = n7_;                       \
    }                                                                         \
    unsigned t_ = (unsigned)(y_ - 8 * lane);                                  \
    if (t_ < 8u) d_ |= 1u << t_;          /* fold x==y for backtrack */       \
    acc |= d_ << (((R) & 3) * 8);                                             \
    if (((R) & 3) == 3) { db32[(y_ >> 2) * 64 + lane] = acc; acc = 0; }       \
} while (0)

#define FWD_ITER(G, CUR, NXT) do {                                \
    int g_ = (G);                                                 \
    if (g_ + 2 < ng) {                                            \
        LOADG(NXT, g_ + 2);  /* prefetch 2 ahead */               \
        WAIT_VM(32);                                              \
    } else if (g_ + 1 < ng) {                                     \
        WAIT_VM(16);                                              \
    } else {                                                      \
        WAIT_VM(0);                                               \
    }                                                             \
    int yb_ = 8 * g_;                                             \
    DPROW(CUR, yb_, 0); DPROW(CUR, yb_, 1);                       \
    DPROW(CUR, yb_, 2); DPROW(CUR, yb_, 3);                       \
    DPROW(CUR, yb_, 4); DPROW(CUR, yb_, 5);                       \
    DPROW(CUR, yb_, 6); DPROW(CUR, yb_, 7);                       \
} while (0)

__global__ __launch_bounds__(64, 1) void k_fwd(const float* __restrict__ neg,
                                               const int* __restrict__ lens,
                                               uint32_t* __restrict__ dirs) {
    int b = blockIdx.x, lane = threadIdx.x;
    const float* nc4 = neg + (size_t)b * TYY * TXX;   // byte math in LOADG
    uint32_t* db32 = dirs + (size_t)b * (TYY / 4) * 64;
    int slen = lens[8 + b];
    int ng = (slen + 7) >> 3;    // 192..256 (slen >= 1536)

    float v[8];
#pragma unroll
    for (int j = 0; j < 8; ++j) v[j] = NEG_INF;
    unsigned acc = 0;

    f32x4 bufA[16], bufB[16], bufC[16];  // 3 groups in flight, asm-pinned
    LOADG(bufA, 0);
    LOADG(bufB, 1);

    for (int p = 0; p < ng; p += 3) {
        FWD_ITER(p, bufA, bufC);
        if (p + 1 < ng) FWD_ITER(p + 1, bufB, bufA);
        if (p + 2 < ng) FWD_ITER(p + 2, bufC, bufB);
    }
}

// MAS backtrack: 32-row slabs; lane j holds a 64-bit window of row y0-j's
// bits; move = (idx!=0) & bit (x==y folded in fwd).
__global__ __launch_bounds__(64, 1) void k_bwd(const int* __restrict__ lens,
                                               const uint32_t* __restrict__ dirs,
                                               int* __restrict__ idx_map) {
    int b = blockIdx.x, lane = threadIdx.x;
    const uint32_t* db32 = dirs + (size_t)b * (TYY / 4) * 64;
    int tlen = lens[b], slen = lens[8 + b];

    int idx = tlen - 1;
    int y0 = slen - 1;
    while (y0 >= 0) {
        int nsteps = (y0 + 1 < 32) ? y0 + 1 : 32;
        int y = y0 - lane;
        int yy = (y < 0) ? 0 : y;
        int w0 = (idx >> 5) - 1;
        if (w0 < 0) w0 = 0;
        if (w0 > 14) w0 = 14;
        int qrow = (yy >> 2) * 64;
        int byteoff = (yy & 3) * 8;
        uint32_t lo = 0, hi = 0;
        if (lane < 32) {
#pragma unroll
            for (int k = 0; k < 4; ++k)
                lo |= ((db32[qrow + 4 * w0 + k] >> byteoff) & 0xffu) << (8 * k);
#pragma unroll
            for (int k = 0; k < 4; ++k)
                hi |= ((db32[qrow + 4 * w0 + 4 + k] >> byteoff) & 0xffu) << (8 * k);
        }
        int base = w0 << 5;
        int cap = 0;
#pragma unroll
        for (int j = 0; j < 32; ++j) {
            if (lane == j) cap = idx;
            uint32_t l = (uint32_t)__builtin_amdgcn_readlane((int)lo, j);
            uint32_t h = (uint32_t)__builtin_amdgcn_readlane((int)hi, j);
            int bp = idx - base;              // 0..63
            uint32_t word = (bp & 32) ? h : l;
            int bit = (int)((word >> (bp & 31)) & 1u);
            int move = (int)(idx != 0) & bit;
            idx -= move;
        }
        if (lane < nsteps) idx_map[b * TYY + (y0 - lane)] = cap;
        y0 -= 32;
    }
}

// Scatter path one-hots + duration histogram from idx_map.
__global__ void k_scatter(const int* __restrict__ lens, const int* __restrict__ idx_map,
                          float* __restrict__ out) {
    int i = blockIdx.x * blockDim.x + threadIdx.x;  // B*Ty threads
    int b = i >> 11, y = i & (TYY - 1);
    if (y < lens[8 + b]) {
        int x = idx_map[i];
        out[(size_t)i * TXX + x] = 1.0f;
        atomicAdd(&out[O4 + b * TXX + x], 1.0f);
    }
}

// Gather m_p/logs_p onto spec frames via idx_map; fused KL partial sums.
__global__ __launch_bounds__(256) void k_gather(const float* __restrict__ z_p,
                                                const float* __restrict__ m_p,
                                                const float* __restrict__ logs_p,
                                                const float* __restrict__ logs_q,
                                                const int* __restrict__ lens,
                                                const int* __restrict__ idx_map,
                                                float* __restrict__ out,
                                                float* __restrict__ partials) {
    const int S = BB * CC * TYY / 4;
    int base = blockIdx.x * 256 + threadIdx.x;
    float klsum = 0.f;
#pragma unroll
    for (int r = 0; r < 4; ++r) {
        int i = base + r * S;
        int t = i & (TYY - 1);
        int bc = i >> 11;
        int b = bc / CC;
        float ma = 0.f, la = 0.f;
        if (t < lens[8 + b]) {
            int x = idx_map[b * TYY + t];
            size_t off = (size_t)bc * TXX + x;
            ma = m_p[off];
            la = logs_p[off];
            float zv = z_p[i], lq = logs_q[i];
            float dz = zv - ma;
            klsum += la - lq - 0.5f + 0.5f * dz * dz * expf(-2.0f * la);
        }
        out[O1 + i] = ma;
        out[O2 + i] = la;
    }
    for (int o = 32; o > 0; o >>= 1) klsum += __shfl_down(klsum, o);
    __shared__ float red[4];
    if ((threadIdx.x & 63) == 0) red[threadIdx.x >> 6] = klsum;
    __syncthreads();
    if (threadIdx.x == 0) partials[blockIdx.x] = red[0] + red[1] + red[2] + red[3];
}

__global__ void k_final(const float* __restrict__ partials, const int* __restrict__ lens,
                        float* __restrict__ out) {
    float s = 0.f;
    for (int i = threadIdx.x; i < 3072; i += 256) s += partials[i];
    for (int o = 32; o > 0; o >>= 1) s += __shfl_down(s, o);
    __shared__ float red[4];
    if ((threadIdx.x & 63) == 0) red[threadIdx.x >> 6] = s;
    __syncthreads();
    if (threadIdx.x == 0) {
        float tot = 0.f;
        for (int b = 0; b < 8; ++b) tot += (float)lens[8 + b];
        out[O3] = (red[0] + red[1] + red[2] + red[3]) / tot;
    }
}

extern "C" void kernel_launch(void* const* d_in, const int* in_sizes, int n_in,
                              void* d_out, int out_size, void* d_ws, size_t ws_size,
                              hipStream_t stream) {
    const float* z_p    = (const float*)d_in[0];
    const float* m_p    = (const float*)d_in[1];
    const float* logs_p = (const float*)d_in[2];
    const float* logs_q = (const float*)d_in[3];
    const float* tmask  = (const float*)d_in[4];
    const float* smask  = (const float*)d_in[5];
    float* out = (float*)d_out;
    char* ws = (char*)d_ws;

    float*    neg      = (float*)(ws + WS_NEG);
    float*    sarr     = (float*)(ws + WS_S);
    float*    msr      = (float*)(ws + WS_MSR);
    float*    bias     = (float*)(ws + WS_BIAS);
    uint32_t* dirs     = (uint32_t*)(ws + WS_DIRS);
    int*      idx_map  = (int*)(ws + WS_IDX);
    int*      lens     = (int*)(ws + WS_LENS);
    float*    partials = (float*)(ws + WS_PART);

    hipLaunchKernelGGL(k_zero,    dim3(2048),      dim3(256), 0, stream, out);
    hipLaunchKernelGGL(k_prep,    dim3(3072),      dim3(256), 0, stream, logs_p, m_p, sarr, msr);
    hipLaunchKernelGGL(k_bias,    dim3(64),        dim3(64),  0, stream, logs_p, m_p, msr, bias);
    hipLaunchKernelGGL(k_len,     dim3(8),         dim3(256), 0, stream, tmask, smask, lens);
    hipLaunchKernelGGL(k_gemm,    dim3(8, 16, 8),  dim3(256), 0, stream, z_p, msr, sarr, bias, lens, neg);
    hipLaunchKernelGGL(k_fwd,     dim3(8),         dim3(64),  0, stream, neg, lens, dirs);
    hipLaunchKernelGGL(k_bwd,     dim3(8),         dim3(64),  0, stream, lens, dirs, idx_map);
    hipLaunchKernelGGL(k_scatter, dim3(64),        dim3(256), 0, stream, lens, idx_map, out);
    hipLaunchKernelGGL(k_gather,  dim3(3072),      dim3(256), 0, stream, z_p, m_p, logs_p, logs_q,
                       lens, idx_map, out, partials);
    hipLaunchKernelGGL(k_final,   dim3(1),         dim3(256), 0, stream, partials, lens, out);
}

// Round 11
// 563.087 us; speedup vs baseline: 1.0739x; 1.0739x over previous
//
#include <hip/hip_runtime.h>
#include <cstdint>
#include <cstddef>

// Problem shape (fixed by the reference): B=8, C=192, Tx=512, Ty=2048.
#define BB 8
#define CC 192
#define TXX 512
#define TYY 2048

#define NEG_INF (-1e9f)
#define HALF_LOG_2PI 0.9189385332046727f  // 0.5*log(2*pi)

// ---- output layout (floats, concatenated in return order) ----
#define O1 8388608
#define O2 11534336
#define O3 14680064
#define O4 14680065

// ---- workspace layout (bytes) ----
#define WS_NEG   0           // neg_cent fp32 [B,Ty,Tx]           33,554,432 B
#define WS_S     33554432    // s_p_sq_r [B,C,Tx]                  3,145,728 B
#define WS_MSR   36700160    // m_p * s  [B,C,Tx]                  3,145,728 B
#define WS_BIAS  39845888    // nc1+nc4  [B,Tx]                       16,384 B
#define WS_DIRS  39862272    // dir bits [B,Ty/4,64] dwords        1,048,576 B
#define WS_IDX   40910848    // idx_map  [B,Ty] int                   65,536 B
#define WS_LENS  40976384    // int text_len[8], spec_len[8]             64 B
#define WS_PART  40976448    // kl partials [3072] float              12,288 B

typedef float f32x4 __attribute__((ext_vector_type(4)));

// ---------------------------------------------------------------------------
__global__ void k_zero(float* __restrict__ out) {
    int64_t i = (int64_t)blockIdx.x * blockDim.x + threadIdx.x;
    const int64_t n4 = (int64_t)BB * TYY * TXX / 4;
    float4 z4 = make_float4(0.f, 0.f, 0.f, 0.f);
    float4* p4 = (float4*)out;
    for (int64_t k = i; k < n4; k += (int64_t)gridDim.x * blockDim.x) p4[k] = z4;
    if (i < BB * TXX) out[O4 + i] = 0.0f;
}

__global__ void k_prep(const float* __restrict__ logs_p, const float* __restrict__ m_p,
                       float* __restrict__ s, float* __restrict__ msr) {
    int i = blockIdx.x * blockDim.x + threadIdx.x;
    float lp = logs_p[i], m = m_p[i];
    float sv = expf(-2.0f * lp);
    s[i] = sv;
    msr[i] = m * sv;
}

// 64 blocks x 64 threads -> 64 CUs active (R20; worth ~65us vs 16 blocks).
__global__ void k_bias(const float* __restrict__ logs_p, const float* __restrict__ m_p,
                       const float* __restrict__ msr, float* __restrict__ bias) {
    int i = blockIdx.x * blockDim.x + threadIdx.x;  // B*Tx = 4096 threads
    int b = i >> 9, x = i & (TXX - 1);
    size_t base = (size_t)b * CC * TXX + x;
    const float* lpb = logs_p + base;
    const float* mb  = m_p + base;
    const float* msb = msr + base;
    float acc = 0.f;
#pragma unroll 8
    for (int c = 0; c < CC; ++c)
        acc += -HALF_LOG_2PI - lpb[(size_t)c * TXX] - 0.5f * mb[(size_t)c * TXX] * msb[(size_t)c * TXX];
    bias[i] = acc;
}

__global__ void k_len(const float* __restrict__ tmask, const float* __restrict__ smask,
                      int* __restrict__ lens) {
    __shared__ float red[256];
    int b = blockIdx.x, tid = threadIdx.x;
    float ts = 0.f;
    for (int i = tid; i < TXX; i += 256) ts += tmask[b * TXX + i];
    red[tid] = ts; __syncthreads();
    for (int s = 128; s > 0; s >>= 1) { if (tid < s) red[tid] += red[tid + s]; __syncthreads(); }
    if (tid == 0) lens[b] = (int)(red[0] + 0.5f);
    __syncthreads();
    float ss = 0.f;
    for (int i = tid; i < TYY; i += 256) ss += smask[b * TYY + i];
    red[tid] = ss; __syncthreads();
    for (int s = 128; s > 0; s >>= 1) { if (tid < s) red[tid] += red[tid + s]; __syncthreads(); }
    if (tid == 0) lens[8 + b] = (int)(red[0] + 0.5f);
}

// ---------------------------------------------------------------------------
// neg_cent GEMM (R25: REVERT to R11/R16 64x64 tile, grid (8,32,8)).
// R24 post-mortem: the 64x128/4x8 retile regressed ~+120us. Mechanism:
// halved blocks/CU (2048->1024 grid => 32->16 waves/CU) halved latency
// hiding across the 24 per-block barriers -- this kernel is staging-
// latency-bound, not LDS-issue-bound. The 64x64 tile at 8 blocks/CU is
// the proven config (~60-90us inferred; never appears in top-5).
// Masked tiles exit early (block-uniform); poison in masked region is
// harmless to the DP/backtrack (R14 note).
// ---------------------------------------------------------------------------
__global__ __launch_bounds__(256) void k_gemm(const float* __restrict__ z,
                                              const float* __restrict__ msr,
                                              const float* __restrict__ sarr,
                                              const float* __restrict__ bias,
                                              const int* __restrict__ lens,
                                              float* __restrict__ neg) {
    int x0 = blockIdx.x * 64, t0 = blockIdx.y * 64, b = blockIdx.z;
    if (x0 >= lens[b] || t0 >= lens[8 + b]) return;   // masked tile

    __shared__ float Zs[16][68], Ms[16][68], Ss[16][68];  // +4 pad
    int tid = threadIdx.x;
    int tx = tid & 15, ty = tid >> 4;
    const float* zb = z    + (size_t)b * CC * TYY;
    const float* mb = msr  + (size_t)b * CC * TXX;
    const float* sb = sarr + (size_t)b * CC * TXX;
    int lr = tid >> 4, lc = (tid & 15) * 4;
    float acc[4][4] = {};
    for (int k0 = 0; k0 < CC; k0 += 16) {
        float4 zv = *(const float4*)(zb + (size_t)(k0 + lr) * TYY + t0 + lc);
        float4 mv = *(const float4*)(mb + (size_t)(k0 + lr) * TXX + x0 + lc);
        float4 sv = *(const float4*)(sb + (size_t)(k0 + lr) * TXX + x0 + lc);
        __syncthreads();
        *(float4*)&Zs[lr][lc] = zv;
        *(float4*)&Ms[lr][lc] = mv;
        *(float4*)&Ss[lr][lc] = sv;
        __syncthreads();
#pragma unroll
        for (int k = 0; k < 16; ++k) {
            float4 a4  = *(const float4*)&Zs[k][ty * 4];
            float4 bm4 = *(const float4*)&Ms[k][tx * 4];
            float4 bs4 = *(const float4*)&Ss[k][tx * 4];
            float av[4]  = {a4.x, a4.y, a4.z, a4.w};
            float bmv[4] = {bm4.x, bm4.y, bm4.z, bm4.w};
            float bsv[4] = {bs4.x, bs4.y, bs4.z, bs4.w};
#pragma unroll
            for (int i2 = 0; i2 < 4; ++i2) {
                float a2 = -0.5f * av[i2] * av[i2];
#pragma unroll
                for (int j = 0; j < 4; ++j)
                    acc[i2][j] += av[i2] * bmv[j] + a2 * bsv[j];
            }
        }
    }
    float4 b4 = *(const float4*)(bias + b * TXX + x0 + tx * 4);
    float bv[4] = {b4.x, b4.y, b4.z, b4.w};
#pragma unroll
    for (int i2 = 0; i2 < 4; ++i2) {
        int t = t0 + ty * 4 + i2;
        float4 o;
        o.x = acc[i2][0] + bv[0]; o.y = acc[i2][1] + bv[1];
        o.z = acc[i2][2] + bv[2]; o.w = acc[i2][3] + bv[3];
        *(float4*)(neg + ((size_t)b * TYY + t) * TXX + x0 + tx * 4) = o;
    }
}

// ---------------------------------------------------------------------------
// MAS forward pass v5 (proven best: 187.5-203us measured across rounds).
// One wave per batch, asm-pinned 3-buffer 8-row prefetch, counted vmcnt.
// R25: first config combining v5-fwd + bias@64 + gemm-64x64 simultaneously.
// ---------------------------------------------------------------------------
#define GLOAD4(DST, PTR, OFF)                                             \
    asm volatile("global_load_dwordx4 %0, %1, off offset:" #OFF           \
                 : "=v"(DST) : "v"(PTR) : "memory")

#define WAIT_VM(N) do {                                                   \
    asm volatile("s_waitcnt vmcnt(" #N ")" ::: "memory");                 \
    __builtin_amdgcn_sched_barrier(0);                                    \
} while (0)

// 8 rows x 512 floats; lane owns 32B (two float4) per row. 4 base pointers
// (rows {0,1},{2,3},{4,5},{6,7}), imm offsets {0,16,2048,2064}.
#define LOADG(DST, G) do {                                                \
    const char* p0_ = (const char*)nc4 + (size_t)(G) * 16384 + lane * 32; \
    const char* p2_ = p0_ + 4096;                                         \
    const char* p4_ = p0_ + 8192;                                         \
    const char* p6_ = p0_ + 12288;                                        \
    GLOAD4(DST[0],  p0_, 0);    GLOAD4(DST[1],  p0_, 16);                 \
    GLOAD4(DST[2],  p0_, 2048); GLOAD4(DST[3],  p0_, 2064);               \
    GLOAD4(DST[4],  p2_, 0);    GLOAD4(DST[5],  p2_, 16);                 \
    GLOAD4(DST[6],  p2_, 2048); GLOAD4(DST[7],  p2_, 2064);               \
    GLOAD4(DST[8],  p4_, 0);    GLOAD4(DST[9],  p4_, 16);                 \
    GLOAD4(DST[10], p4_, 2048); GLOAD4(DST[11], p4_, 2064);               \
    GLOAD4(DST[12], p6_, 0);    GLOAD4(DST[13], p6_, 16);                 \
    GLOAD4(DST[14], p6_, 2048); GLOAD4(DST[15], p6_, 2064);               \
} while (0)

#define DPROW(CUR, YB, R) do {                                                \
    int y_ = (YB) + (R);                                                      \
    float s0_ = CUR[2*(R)][0],   s1_ = CUR[2*(R)][1];                         \
    float s2_ = CUR[2*(R)][2],   s3_ = CUR[2*(R)][3];                         \
    float s4_ = CUR[2*(R)+1][0], s5_ = CUR[2*(R)+1][1];                       \
    float s6_ = CUR[2*(R)+1][2], s7_ = CUR[2*(R)+1][3];                       \
    unsigned d_ = 0;                                                          \
    if (y_ == 0) {                                                            \
        if (lane == 0) v[0] = s0_;   /* only x==0 scored on row 0 */          \
    } else {                                                                  \
        float pl_ = __int_as_float(__builtin_amdgcn_update_dpp(               \
            0, __float_as_int(v[7]), 0x138, 0xF, 0xF, false));                \
        if (lane == 0) pl_ = NEG_INF;                                         \
        float n0_ = s0_ + fmaxf(v[0], pl_);  if (pl_  > v[0]) d_ |= 1u;       \
        float n1_ = s1_ + fmaxf(v[1], v[0]); if (v[0] > v[1]) d_ |= 2u;       \
        float n2_ = s2_ + fmaxf(v[2], v[1]); if (v[1] > v[2]) d_ |= 4u;       \
        float n3_ = s3_ + fmaxf(v[3], v[2]); if (v[2] > v[3]) d_ |= 8u;       \
        float n4_ = s4_ + fmaxf(v[4], v[3]); if (v[3] > v[4]) d_ |= 16u;      \
        float n5_ = s5_ + fmaxf(v[5], v[4]); if (v[4] > v[5]) d_ |= 32u;      \
        float n6_ = s6_ + fmaxf(v[6], v[5]); if (v[5] > v[6]) d_ |= 64u;      \
        float n7_ = s7_ + fmaxf(v[7], v[6]); if (v[6] > v[7]) d_ |= 128u;     \
        v[0] = n0_; v[1] = n1_; v[2] = n2_; v[3] = n3_;                       \
        v[4] = n4_; v[5] = n5_; v[6] = n6_; v[7] = n7_;                       \
    }                                                                         \
    unsigned t_ = (unsigned)(y_ - 8 * lane);                                  \
    if (t_ < 8u) d_ |= 1u << t_;          /* fold x==y for backtrack */       \
    acc |= d_ << (((R) & 3) * 8);                                             \
    if (((R) & 3) == 3) { db32[(y_ >> 2) * 64 + lane] = acc; acc = 0; }       \
} while (0)

#define FWD_ITER(G, CUR, NXT) do {                                \
    int g_ = (G);                                                 \
    if (g_ + 2 < ng) {                                            \
        LOADG(NXT, g_ + 2);  /* prefetch 2 ahead */               \
        WAIT_VM(32);                                              \
    } else if (g_ + 1 < ng) {                                     \
        WAIT_VM(16);                                              \
    } else {                                                      \
        WAIT_VM(0);                                               \
    }                                                             \
    int yb_ = 8 * g_;                                             \
    DPROW(CUR, yb_, 0); DPROW(CUR, yb_, 1);                       \
    DPROW(CUR, yb_, 2); DPROW(CUR, yb_, 3);                       \
    DPROW(CUR, yb_, 4); DPROW(CUR, yb_, 5);                       \
    DPROW(CUR, yb_, 6); DPROW(CUR, yb_, 7);                       \
} while (0)

__global__ __launch_bounds__(64, 1) void k_fwd(const float* __restrict__ neg,
                                               const int* __restrict__ lens,
                                               uint32_t* __restrict__ dirs) {
    int b = blockIdx.x, lane = threadIdx.x;
    const float* nc4 = neg + (size_t)b * TYY * TXX;   // byte math in LOADG
    uint32_t* db32 = dirs + (size_t)b * (TYY / 4) * 64;
    int slen = lens[8 + b];
    int ng = (slen + 7) >> 3;    // 192..256 (slen >= 1536)

    float v[8];
#pragma unroll
    for (int j = 0; j < 8; ++j) v[j] = NEG_INF;
    unsigned acc = 0;

    f32x4 bufA[16], bufB[16], bufC[16];  // 3 groups in flight, asm-pinned
    LOADG(bufA, 0);
    LOADG(bufB, 1);

    for (int p = 0; p < ng; p += 3) {
        FWD_ITER(p, bufA, bufC);
        if (p + 1 < ng) FWD_ITER(p + 1, bufB, bufA);
        if (p + 2 < ng) FWD_ITER(p + 2, bufC, bufB);
    }
}

// MAS backtrack: 32-row slabs; lane j holds a 64-bit window of row y0-j's
// bits; move = (idx!=0) & bit (x==y folded in fwd).
__global__ __launch_bounds__(64, 1) void k_bwd(const int* __restrict__ lens,
                                               const uint32_t* __restrict__ dirs,
                                               int* __restrict__ idx_map) {
    int b = blockIdx.x, lane = threadIdx.x;
    const uint32_t* db32 = dirs + (size_t)b * (TYY / 4) * 64;
    int tlen = lens[b], slen = lens[8 + b];

    int idx = tlen - 1;
    int y0 = slen - 1;
    while (y0 >= 0) {
        int nsteps = (y0 + 1 < 32) ? y0 + 1 : 32;
        int y = y0 - lane;
        int yy = (y < 0) ? 0 : y;
        int w0 = (idx >> 5) - 1;
        if (w0 < 0) w0 = 0;
        if (w0 > 14) w0 = 14;
        int qrow = (yy >> 2) * 64;
        int byteoff = (yy & 3) * 8;
        uint32_t lo = 0, hi = 0;
        if (lane < 32) {
#pragma unroll
            for (int k = 0; k < 4; ++k)
                lo |= ((db32[qrow + 4 * w0 + k] >> byteoff) & 0xffu) << (8 * k);
#pragma unroll
            for (int k = 0; k < 4; ++k)
                hi |= ((db32[qrow + 4 * w0 + 4 + k] >> byteoff) & 0xffu) << (8 * k);
        }
        int base = w0 << 5;
        int cap = 0;
#pragma unroll
        for (int j = 0; j < 32; ++j) {
            if (lane == j) cap = idx;
            uint32_t l = (uint32_t)__builtin_amdgcn_readlane((int)lo, j);
            uint32_t h = (uint32_t)__builtin_amdgcn_readlane((int)hi, j);
            int bp = idx - base;              // 0..63
            uint32_t word = (bp & 32) ? h : l;
            int bit = (int)((word >> (bp & 31)) & 1u);
            int move = (int)(idx != 0) & bit;
            idx -= move;
        }
        if (lane < nsteps) idx_map[b * TYY + (y0 - lane)] = cap;
        y0 -= 32;
    }
}

// Scatter path one-hots + duration histogram from idx_map.
__global__ void k_scatter(const int* __restrict__ lens, const int* __restrict__ idx_map,
                          float* __restrict__ out) {
    int i = blockIdx.x * blockDim.x + threadIdx.x;  // B*Ty threads
    int b = i >> 11, y = i & (TYY - 1);
    if (y < lens[8 + b]) {
        int x = idx_map[i];
        out[(size_t)i * TXX + x] = 1.0f;
        atomicAdd(&out[O4 + b * TXX + x], 1.0f);
    }
}

// Gather m_p/logs_p onto spec frames via idx_map; fused KL partial sums.
__global__ __launch_bounds__(256) void k_gather(const float* __restrict__ z_p,
                                                const float* __restrict__ m_p,
                                                const float* __restrict__ logs_p,
                                                const float* __restrict__ logs_q,
                                                const int* __restrict__ lens,
                                                const int* __restrict__ idx_map,
                                                float* __restrict__ out,
                                                float* __restrict__ partials) {
    const int S = BB * CC * TYY / 4;
    int base = blockIdx.x * 256 + threadIdx.x;
    float klsum = 0.f;
#pragma unroll
    for (int r = 0; r < 4; ++r) {
        int i = base + r * S;
        int t = i & (TYY - 1);
        int bc = i >> 11;
        int b = bc / CC;
        float ma = 0.f, la = 0.f;
        if (t < lens[8 + b]) {
            int x = idx_map[b * TYY + t];
            size_t off = (size_t)bc * TXX + x;
            ma = m_p[off];
            la = logs_p[off];
            float zv = z_p[i], lq = logs_q[i];
            float dz = zv - ma;
            klsum += la - lq - 0.5f + 0.5f * dz * dz * expf(-2.0f * la);
        }
        out[O1 + i] = ma;
        out[O2 + i] = la;
    }
    for (int o = 32; o > 0; o >>= 1) klsum += __shfl_down(klsum, o);
    __shared__ float red[4];
    if ((threadIdx.x & 63) == 0) red[threadIdx.x >> 6] = klsum;
    __syncthreads();
    if (threadIdx.x == 0) partials[blockIdx.x] = red[0] + red[1] + red[2] + red[3];
}

__global__ void k_final(const float* __restrict__ partials, const int* __restrict__ lens,
                        float* __restrict__ out) {
    float s = 0.f;
    for (int i = threadIdx.x; i < 3072; i += 256) s += partials[i];
    for (int o = 32; o > 0; o >>= 1) s += __shfl_down(s, o);
    __shared__ float red[4];
    if ((threadIdx.x & 63) == 0) red[threadIdx.x >> 6] = s;
    __syncthreads();
    if (threadIdx.x == 0) {
        float tot = 0.f;
        for (int b = 0; b < 8; ++b) tot += (float)lens[8 + b];
        out[O3] = (red[0] + red[1] + red[2] + red[3]) / tot;
    }
}

extern "C" void kernel_launch(void* const* d_in, const int* in_sizes, int n_in,
                              void* d_out, int out_size, void* d_ws, size_t ws_size,
                              hipStream_t stream) {
    const float* z_p    = (const float*)d_in[0];
    const float* m_p    = (const float*)d_in[1];
    const float* logs_p = (const float*)d_in[2];
    const float* logs_q = (const float*)d_in[3];
    const float* tmask  = (const float*)d_in[4];
    const float* smask  = (const float*)d_in[5];
    float* out = (float*)d_out;
    char* ws = (char*)d_ws;

    float*    neg      = (float*)(ws + WS_NEG);
    float*    sarr     = (float*)(ws + WS_S);
    float*    msr      = (float*)(ws + WS_MSR);
    float*    bias     = (float*)(ws + WS_BIAS);
    uint32_t* dirs     = (uint32_t*)(ws + WS_DIRS);
    int*      idx_map  = (int*)(ws + WS_IDX);
    int*      lens     = (int*)(ws + WS_LENS);
    float*    partials = (float*)(ws + WS_PART);

    hipLaunchKernelGGL(k_zero,    dim3(2048),      dim3(256), 0, stream, out);
    hipLaunchKernelGGL(k_prep,    dim3(3072),      dim3(256), 0, stream, logs_p, m_p, sarr, msr);
    hipLaunchKernelGGL(k_bias,    dim3(64),        dim3(64),  0, stream, logs_p, m_p, msr, bias);
    hipLaunchKernelGGL(k_len,     dim3(8),         dim3(256), 0, stream, tmask, smask, lens);
    hipLaunchKernelGGL(k_gemm,    dim3(8, 32, 8),  dim3(256), 0, stream, z_p, msr, sarr, bias, lens, neg);
    hipLaunchKernelGGL(k_fwd,     dim3(8),         dim3(64),  0, stream, neg, lens, dirs);
    hipLaunchKernelGGL(k_bwd,     dim3(8),         dim3(64),  0, stream, lens, dirs, idx_map);
    hipLaunchKernelGGL(k_scatter, dim3(64),        dim3(256), 0, stream, lens, idx_map, out);
    hipLaunchKernelGGL(k_gather,  dim3(3072),      dim3(256), 0, stream, z_p, m_p, logs_p, logs_q,
                       lens, idx_map, out, partials);
    hipLaunchKernelGGL(k_final,   dim3(1),         dim3(256), 0, stream, partials, lens, out);
}

// Round 12
// 525.434 us; speedup vs baseline: 1.1509x; 1.0717x over previous
//
#include <hip/hip_runtime.h>
#include <cstdint>
#include <cstddef>

// Problem shape (fixed by the reference): B=8, C=192, Tx=512, Ty=2048.
#define BB 8
#define CC 192
#define TXX 512
#define TYY 2048

#define NEG_INF (-1e9f)
#define HALF_LOG_2PI 0.9189385332046727f  // 0.5*log(2*pi)

// ---- output layout (floats, concatenated in return order) ----
#define O1 8388608
#define O2 11534336
#define O3 14680064
#define O4 14680065

// ---- workspace layout (bytes) ----
#define WS_NEG   0           // neg_cent fp32 [B,Ty,Tx]           33,554,432 B
#define WS_S     33554432    // s_p_sq_r [B,C,Tx]                  3,145,728 B
#define WS_MSR   36700160    // m_p * s  [B,C,Tx]                  3,145,728 B
#define WS_BIAS  39845888    // nc1+nc4  [B,Tx]                       16,384 B
#define WS_DIRS  39862272    // dir bits [B,Ty/4,64] dwords        1,048,576 B
#define WS_IDX   40910848    // idx_map  [B,Ty] int                   65,536 B
#define WS_LENS  40976384    // int text_len[8], spec_len[8]             64 B
#define WS_PART  40976448    // kl partials [3072] float              12,288 B

typedef float f32x4 __attribute__((ext_vector_type(4)));

// ---------------------------------------------------------------------------
// k_pre (R26): fused k_zero + k_prep + k_bias + k_len (all independent).
// bias recomputes msv = m*expf(-2lp) locally with the IDENTICAL expression
// tree as k_prep stored (bitwise-same), removing the prep->bias dependency.
// Saves 3 launch gaps.
// ---------------------------------------------------------------------------
#define PRE_NZERO 2048
#define PRE_NPREP 3072
#define PRE_NBIAS 16
#define PRE_NLEN  8
__global__ __launch_bounds__(256) void k_pre(const float* __restrict__ logs_p,
                                             const float* __restrict__ m_p,
                                             const float* __restrict__ tmask,
                                             const float* __restrict__ smask,
                                             float* __restrict__ s,
                                             float* __restrict__ msr,
                                             float* __restrict__ bias,
                                             int* __restrict__ lens,
                                             float* __restrict__ out) {
    int blk = blockIdx.x, tid = threadIdx.x;
    if (blk < PRE_NZERO) {
        // ---- zero path output + duration histogram ----
        int64_t i = (int64_t)blk * 256 + tid;
        const int64_t n4 = (int64_t)BB * TYY * TXX / 4;
        float4 z4 = make_float4(0.f, 0.f, 0.f, 0.f);
        float4* p4 = (float4*)out;
        for (int64_t k = i; k < n4; k += (int64_t)PRE_NZERO * 256) p4[k] = z4;
        if (i < BB * TXX) out[O4 + i] = 0.0f;
    } else if (blk < PRE_NZERO + PRE_NPREP) {
        // ---- prep: s = exp(-2 logs_p), msr = m_p * s ----
        int i = (blk - PRE_NZERO) * 256 + tid;
        float lp = logs_p[i], m = m_p[i];
        float sv = expf(-2.0f * lp);
        s[i] = sv;
        msr[i] = m * sv;
    } else if (blk < PRE_NZERO + PRE_NPREP + PRE_NBIAS) {
        // ---- bias: nc1 + nc4 per (b, x) ----
        int i = (blk - PRE_NZERO - PRE_NPREP) * 256 + tid;  // B*Tx = 4096
        int b = i >> 9, x = i & (TXX - 1);
        size_t base = (size_t)b * CC * TXX + x;
        const float* lpb = logs_p + base;
        const float* mb  = m_p + base;
        float acc = 0.f;
#pragma unroll 8
        for (int c = 0; c < CC; ++c) {
            float lp = lpb[(size_t)c * TXX];
            float m  = mb[(size_t)c * TXX];
            float msv = m * expf(-2.0f * lp);   // == msr[c] bitwise
            acc += -HALF_LOG_2PI - lp - 0.5f * m * msv;
        }
        bias[i] = acc;
    } else {
        // ---- len: per-batch mask sums ----
        __shared__ float red[256];
        int b = blk - (PRE_NZERO + PRE_NPREP + PRE_NBIAS);
        float ts = 0.f;
        for (int i = tid; i < TXX; i += 256) ts += tmask[b * TXX + i];
        red[tid] = ts; __syncthreads();
        for (int s2 = 128; s2 > 0; s2 >>= 1) { if (tid < s2) red[tid] += red[tid + s2]; __syncthreads(); }
        if (tid == 0) lens[b] = (int)(red[0] + 0.5f);
        __syncthreads();
        float ss = 0.f;
        for (int i = tid; i < TYY; i += 256) ss += smask[b * TYY + i];
        red[tid] = ss; __syncthreads();
        for (int s2 = 128; s2 > 0; s2 >>= 1) { if (tid < s2) red[tid] += red[tid + s2]; __syncthreads(); }
        if (tid == 0) lens[8 + b] = (int)(red[0] + 0.5f);
    }
}

// ---------------------------------------------------------------------------
// neg_cent GEMM (proven R11/R16 64x64 tile, grid (8,32,8), 8 blocks/CU).
// Masked tiles exit early (block-uniform); poison in masked region is
// harmless to the DP/backtrack (R14 note).
// ---------------------------------------------------------------------------
__global__ __launch_bounds__(256) void k_gemm(const float* __restrict__ z,
                                              const float* __restrict__ msr,
                                              const float* __restrict__ sarr,
                                              const float* __restrict__ bias,
                                              const int* __restrict__ lens,
                                              float* __restrict__ neg) {
    int x0 = blockIdx.x * 64, t0 = blockIdx.y * 64, b = blockIdx.z;
    if (x0 >= lens[b] || t0 >= lens[8 + b]) return;   // masked tile

    __shared__ float Zs[16][68], Ms[16][68], Ss[16][68];  // +4 pad
    int tid = threadIdx.x;
    int tx = tid & 15, ty = tid >> 4;
    const float* zb = z    + (size_t)b * CC * TYY;
    const float* mb = msr  + (size_t)b * CC * TXX;
    const float* sb = sarr + (size_t)b * CC * TXX;
    int lr = tid >> 4, lc = (tid & 15) * 4;
    float acc[4][4] = {};
    for (int k0 = 0; k0 < CC; k0 += 16) {
        float4 zv = *(const float4*)(zb + (size_t)(k0 + lr) * TYY + t0 + lc);
        float4 mv = *(const float4*)(mb + (size_t)(k0 + lr) * TXX + x0 + lc);
        float4 sv = *(const float4*)(sb + (size_t)(k0 + lr) * TXX + x0 + lc);
        __syncthreads();
        *(float4*)&Zs[lr][lc] = zv;
        *(float4*)&Ms[lr][lc] = mv;
        *(float4*)&Ss[lr][lc] = sv;
        __syncthreads();
#pragma unroll
        for (int k = 0; k < 16; ++k) {
            float4 a4  = *(const float4*)&Zs[k][ty * 4];
            float4 bm4 = *(const float4*)&Ms[k][tx * 4];
            float4 bs4 = *(const float4*)&Ss[k][tx * 4];
            float av[4]  = {a4.x, a4.y, a4.z, a4.w};
            float bmv[4] = {bm4.x, bm4.y, bm4.z, bm4.w};
            float bsv[4] = {bs4.x, bs4.y, bs4.z, bs4.w};
#pragma unroll
            for (int i2 = 0; i2 < 4; ++i2) {
                float a2 = -0.5f * av[i2] * av[i2];
#pragma unroll
                for (int j = 0; j < 4; ++j)
                    acc[i2][j] += av[i2] * bmv[j] + a2 * bsv[j];
            }
        }
    }
    float4 b4 = *(const float4*)(bias + b * TXX + x0 + tx * 4);
    float bv[4] = {b4.x, b4.y, b4.z, b4.w};
#pragma unroll
    for (int i2 = 0; i2 < 4; ++i2) {
        int t = t0 + ty * 4 + i2;
        float4 o;
        o.x = acc[i2][0] + bv[0]; o.y = acc[i2][1] + bv[1];
        o.z = acc[i2][2] + bv[2]; o.w = acc[i2][3] + bv[3];
        *(float4*)(neg + ((size_t)b * TYY + t) * TXX + x0 + tx * 4) = o;
    }
}

// ---------------------------------------------------------------------------
// MAS forward pass v5 (proven best: 187.5 us reproducible). UNTOUCHED.
// One wave per batch, asm-pinned 3-buffer 8-row prefetch, counted vmcnt.
// ---------------------------------------------------------------------------
#define GLOAD4(DST, PTR, OFF)                                             \
    asm volatile("global_load_dwordx4 %0, %1, off offset:" #OFF           \
                 : "=v"(DST) : "v"(PTR) : "memory")

#define WAIT_VM(N) do {                                                   \
    asm volatile("s_waitcnt vmcnt(" #N ")" ::: "memory");                 \
    __builtin_amdgcn_sched_barrier(0);                                    \
} while (0)

#define LOADG(DST, G) do {                                                \
    const char* p0_ = (const char*)nc4 + (size_t)(G) * 16384 + lane * 32; \
    const char* p2_ = p0_ + 4096;                                         \
    const char* p4_ = p0_ + 8192;                                         \
    const char* p6_ = p0_ + 12288;                                        \
    GLOAD4(DST[0],  p0_, 0);    GLOAD4(DST[1],  p0_, 16);                 \
    GLOAD4(DST[2],  p0_, 2048); GLOAD4(DST[3],  p0_, 2064);               \
    GLOAD4(DST[4],  p2_, 0);    GLOAD4(DST[5],  p2_, 16);                 \
    GLOAD4(DST[6],  p2_, 2048); GLOAD4(DST[7],  p2_, 2064);               \
    GLOAD4(DST[8],  p4_, 0);    GLOAD4(DST[9],  p4_, 16);                 \
    GLOAD4(DST[10], p4_, 2048); GLOAD4(DST[11], p4_, 2064);               \
    GLOAD4(DST[12], p6_, 0);    GLOAD4(DST[13], p6_, 16);                 \
    GLOAD4(DST[14], p6_, 2048); GLOAD4(DST[15], p6_, 2064);               \
} while (0)

#define DPROW(CUR, YB, R) do {                                                \
    int y_ = (YB) + (R);                                                      \
    float s0_ = CUR[2*(R)][0],   s1_ = CUR[2*(R)][1];                         \
    float s2_ = CUR[2*(R)][2],   s3_ = CUR[2*(R)][3];                         \
    float s4_ = CUR[2*(R)+1][0], s5_ = CUR[2*(R)+1][1];                       \
    float s6_ = CUR[2*(R)+1][2], s7_ = CUR[2*(R)+1][3];                       \
    unsigned d_ = 0;                                                          \
    if (y_ == 0) {                                                            \
        if (lane == 0) v[0] = s0_;   /* only x==0 scored on row 0 */          \
    } else {                                                                  \
        float pl_ = __int_as_float(__builtin_amdgcn_update_dpp(               \
            0, __float_as_int(v[7]), 0x138, 0xF, 0xF, false));                \
        if (lane == 0) pl_ = NEG_INF;                                         \
        float n0_ = s0_ + fmaxf(v[0], pl_);  if (pl_  > v[0]) d_ |= 1u;       \
        float n1_ = s1_ + fmaxf(v[1], v[0]); if (v[0] > v[1]) d_ |= 2u;       \
        float n2_ = s2_ + fmaxf(v[2], v[1]); if (v[1] > v[2]) d_ |= 4u;       \
        float n3_ = s3_ + fmaxf(v[3], v[2]); if (v[2] > v[3]) d_ |= 8u;       \
        float n4_ = s4_ + fmaxf(v[4], v[3]); if (v[3] > v[4]) d_ |= 16u;      \
        float n5_ = s5_ + fmaxf(v[5], v[4]); if (v[4] > v[5]) d_ |= 32u;      \
        float n6_ = s6_ + fmaxf(v[6], v[5]); if (v[5] > v[6]) d_ |= 64u;      \
        float n7_ = s7_ + fmaxf(v[7], v[6]); if (v[6] > v[7]) d_ |= 128u;     \
        v[0] = n0_; v[1] = n1_; v[2] = n2_; v[3] = n3_;                       \
        v[4] = n4_; v[5] = n5_; v[6] = n6_; v[7] = n7_;                       \
    }                                                                         \
    unsigned t_ = (unsigned)(y_ - 8 * lane);                                  \
    if (t_ < 8u) d_ |= 1u << t_;          /* fold x==y for backtrack */       \
    acc |= d_ << (((R) & 3) * 8);                                             \
    if (((R) & 3) == 3) { db32[(y_ >> 2) * 64 + lane] = acc; acc = 0; }       \
} while (0)

#define FWD_ITER(G, CUR, NXT) do {                                \
    int g_ = (G);                                                 \
    if (g_ + 2 < ng) {                                            \
        LOADG(NXT, g_ + 2);  /* prefetch 2 ahead */               \
        WAIT_VM(32);                                              \
    } else if (g_ + 1 < ng) {                                     \
        WAIT_VM(16);                                              \
    } else {                                                      \
        WAIT_VM(0);                                               \
    }                                                             \
    int yb_ = 8 * g_;                                             \
    DPROW(CUR, yb_, 0); DPROW(CUR, yb_, 1);                       \
    DPROW(CUR, yb_, 2); DPROW(CUR, yb_, 3);                       \
    DPROW(CUR, yb_, 4); DPROW(CUR, yb_, 5);                       \
    DPROW(CUR, yb_, 6); DPROW(CUR, yb_, 7);                       \
} while (0)

__global__ __launch_bounds__(64, 1) void k_fwd(const float* __restrict__ neg,
                                               const int* __restrict__ lens,
                                               uint32_t* __restrict__ dirs) {
    int b = blockIdx.x, lane = threadIdx.x;
    const float* nc4 = neg + (size_t)b * TYY * TXX;   // byte math in LOADG
    uint32_t* db32 = dirs + (size_t)b * (TYY / 4) * 64;
    int slen = lens[8 + b];
    int ng = (slen + 7) >> 3;    // 192..256 (slen >= 1536)

    float v[8];
#pragma unroll
    for (int j = 0; j < 8; ++j) v[j] = NEG_INF;
    unsigned acc = 0;

    f32x4 bufA[16], bufB[16], bufC[16];  // 3 groups in flight, asm-pinned
    LOADG(bufA, 0);
    LOADG(bufB, 1);

    for (int p = 0; p < ng; p += 3) {
        FWD_ITER(p, bufA, bufC);
        if (p + 1 < ng) FWD_ITER(p + 1, bufB, bufA);
        if (p + 2 < ng) FWD_ITER(p + 2, bufC, bufB);
    }
}

// ---------------------------------------------------------------------------
// MAS backtrack v2 (R26): software-pipelined window prefetch + fused scatter.
//
// R25 accounting: bwd ~100us (+-30) -- the largest non-fwd item. Old
// structure: per slab, 8 scattered idx-dependent loads SERIAL before the
// 32-step chain (dirs L2-evicted by fwd's 33.5MB neg stream -> ~500-900cy).
// v2: entry idx of slab k+1 is in [idx_k-32, idx_k], and (x>>5)-((x-32)>>5)
// == 1 always, so slab k+1's 64-bit window lies inside a 3-word window with
// base wb = clamp(((idx_k-32)>>5)-1, 0, 13), computable at slab-k START.
// Prefetch (12 dwords + byte-packing, independent of the chain) overlaps
// slab k's inner loop; slab k+1 selects lo/hi with s = clamp(w0-wb,0,1)
// (algebra incl. clamp edges verified: base (wb+s)<<5 == w0<<5 always).
// Also dropped the redundant (idx!=0) check: stored bit at x=0 is 0 for all
// y>0 (lane0 pl=NEG_INF strict-less; x==y fold only at y=0); post-y=0
// garbage moves happen after the last cap capture -> harmless.
// Scatter fused into the store step (same (b,y,cap) set as k_scatter).
// ---------------------------------------------------------------------------
#define LOADW(D0, D1, D2, WB, QROW, BOFF) do {                            \
    const uint32_t* p_ = db32 + (QROW) + 4 * (WB);                        \
    uint32_t a0_=p_[0], a1_=p_[1], a2_=p_[2],  a3_=p_[3];                 \
    uint32_t b0_=p_[4], b1_=p_[5], b2_=p_[6],  b3_=p_[7];                 \
    uint32_t c0_=p_[8], c1_=p_[9], c2_=p_[10], c3_=p_[11];                \
    D0 = ((a0_>>(BOFF))&0xffu)        | (((a1_>>(BOFF))&0xffu)<<8) |      \
         (((a2_>>(BOFF))&0xffu)<<16)  | (((a3_>>(BOFF))&0xffu)<<24);      \
    D1 = ((b0_>>(BOFF))&0xffu)        | (((b1_>>(BOFF))&0xffu)<<8) |      \
         (((b2_>>(BOFF))&0xffu)<<16)  | (((b3_>>(BOFF))&0xffu)<<24);      \
    D2 = ((c0_>>(BOFF))&0xffu)        | (((c1_>>(BOFF))&0xffu)<<8) |      \
         (((c2_>>(BOFF))&0xffu)<<16)  | (((c3_>>(BOFF))&0xffu)<<24);      \
} while (0)

__global__ __launch_bounds__(64, 1) void k_bwd(const int* __restrict__ lens,
                                               const uint32_t* __restrict__ dirs,
                                               int* __restrict__ idx_map,
                                               float* __restrict__ out) {
    int b = blockIdx.x, lane = threadIdx.x;
    const uint32_t* db32 = dirs + (size_t)b * (TYY / 4) * 64;
    int tlen = lens[b], slen = lens[8 + b];

    int idx = tlen - 1;
    int y0 = slen - 1;
    int wb;
    uint32_t W0 = 0, W1 = 0, W2 = 0;
    {   // prologue: window for slab 0 (exact w0 known; wb = min(w0,13))
        int yy = y0 - lane; if (yy < 0) yy = 0;
        int qrow = (yy >> 2) * 64, boff = (yy & 3) * 8;
        int t = (idx >> 5) - 1; if (t < 0) t = 0; if (t > 13) t = 13;
        wb = t;
        if (lane < 32) LOADW(W0, W1, W2, wb, qrow, boff);
    }
    while (y0 >= 0) {
        int w0 = (idx >> 5) - 1; if (w0 < 0) w0 = 0; if (w0 > 14) w0 = 14;
        int s = w0 - wb; if (s < 0) s = 0; if (s > 1) s = 1;
        uint32_t lo = s ? W1 : W0;
        uint32_t hi = s ? W2 : W1;
        int base = (wb + s) << 5;
        // ---- prefetch next slab's window (off the idx chain) ----
        uint32_t N0 = 0, N1 = 0, N2 = 0;
        int idxm = idx - 32; if (idxm < 0) idxm = 0;
        int wbn = (idxm >> 5) - 1; if (wbn < 0) wbn = 0; if (wbn > 13) wbn = 13;
        {
            int yn = y0 - 32 - lane; if (yn < 0) yn = 0;
            int qn = (yn >> 2) * 64, bn = (yn & 3) * 8;
            if (lane < 32) LOADW(N0, N1, N2, wbn, qn, bn);
        }
        int nsteps = (y0 + 1 < 32) ? y0 + 1 : 32;
        int cap = 0;
#pragma unroll
        for (int j = 0; j < 32; ++j) {
            if (lane == j) cap = idx;
            uint32_t l = (uint32_t)__builtin_amdgcn_readlane((int)lo, j);
            uint32_t h = (uint32_t)__builtin_amdgcn_readlane((int)hi, j);
            int bp = idx - base;              // 0..63 within slab
            uint32_t word = (bp & 32) ? h : l;
            idx -= (int)((word >> (bp & 31)) & 1u);
        }
        if (lane < nsteps) {
            int y = y0 - lane;
            idx_map[b * TYY + y] = cap;
            out[((size_t)(b * TYY + y)) * TXX + cap] = 1.0f;       // scatter
            atomicAdd(&out[O4 + b * TXX + cap], 1.0f);             // duration
        }
        wb = wbn; W0 = N0; W1 = N1; W2 = N2;
        y0 -= 32;
    }
}

// Gather m_p/logs_p onto spec frames via idx_map; fused KL partial sums.
__global__ __launch_bounds__(256) void k_gather(const float* __restrict__ z_p,
                                                const float* __restrict__ m_p,
                                                const float* __restrict__ logs_p,
                                                const float* __restrict__ logs_q,
                                                const int* __restrict__ lens,
                                                const int* __restrict__ idx_map,
                                                float* __restrict__ out,
                                                float* __restrict__ partials) {
    const int S = BB * CC * TYY / 4;
    int base = blockIdx.x * 256 + threadIdx.x;
    float klsum = 0.f;
#pragma unroll
    for (int r = 0; r < 4; ++r) {
        int i = base + r * S;
        int t = i & (TYY - 1);
        int bc = i >> 11;
        int b = bc / CC;
        float ma = 0.f, la = 0.f;
        if (t < lens[8 + b]) {
            int x = idx_map[b * TYY + t];
            size_t off = (size_t)bc * TXX + x;
            ma = m_p[off];
            la = logs_p[off];
            float zv = z_p[i], lq = logs_q[i];
            float dz = zv - ma;
            klsum += la - lq - 0.5f + 0.5f * dz * dz * expf(-2.0f * la);
        }
        out[O1 + i] = ma;
        out[O2 + i] = la;
    }
    for (int o = 32; o > 0; o >>= 1) klsum += __shfl_down(klsum, o);
    __shared__ float red[4];
    if ((threadIdx.x & 63) == 0) red[threadIdx.x >> 6] = klsum;
    __syncthreads();
    if (threadIdx.x == 0) partials[blockIdx.x] = red[0] + red[1] + red[2] + red[3];
}

__global__ void k_final(const float* __restrict__ partials, const int* __restrict__ lens,
                        float* __restrict__ out) {
    float s = 0.f;
    for (int i = threadIdx.x; i < 3072; i += 256) s += partials[i];
    for (int o = 32; o > 0; o >>= 1) s += __shfl_down(s, o);
    __shared__ float red[4];
    if ((threadIdx.x & 63) == 0) red[threadIdx.x >> 6] = s;
    __syncthreads();
    if (threadIdx.x == 0) {
        float tot = 0.f;
        for (int b = 0; b < 8; ++b) tot += (float)lens[8 + b];
        out[O3] = (red[0] + red[1] + red[2] + red[3]) / tot;
    }
}

extern "C" void kernel_launch(void* const* d_in, const int* in_sizes, int n_in,
                              void* d_out, int out_size, void* d_ws, size_t ws_size,
                              hipStream_t stream) {
    const float* z_p    = (const float*)d_in[0];
    const float* m_p    = (const float*)d_in[1];
    const float* logs_p = (const float*)d_in[2];
    const float* logs_q = (const float*)d_in[3];
    const float* tmask  = (const float*)d_in[4];
    const float* smask  = (const float*)d_in[5];
    float* out = (float*)d_out;
    char* ws = (char*)d_ws;

    float*    neg      = (float*)(ws + WS_NEG);
    float*    sarr     = (float*)(ws + WS_S);
    float*    msr      = (float*)(ws + WS_MSR);
    float*    bias     = (float*)(ws + WS_BIAS);
    uint32_t* dirs     = (uint32_t*)(ws + WS_DIRS);
    int*      idx_map  = (int*)(ws + WS_IDX);
    int*      lens     = (int*)(ws + WS_LENS);
    float*    partials = (float*)(ws + WS_PART);

    hipLaunchKernelGGL(k_pre, dim3(PRE_NZERO + PRE_NPREP + PRE_NBIAS + PRE_NLEN),
                       dim3(256), 0, stream,
                       logs_p, m_p, tmask, smask, sarr, msr, bias, lens, out);
    hipLaunchKernelGGL(k_gemm,   dim3(8, 32, 8), dim3(256), 0, stream,
                       z_p, msr, sarr, bias, lens, neg);
    hipLaunchKernelGGL(k_fwd,    dim3(8),        dim3(64),  0, stream, neg, lens, dirs);
    hipLaunchKernelGGL(k_bwd,    dim3(8),        dim3(64),  0, stream, lens, dirs, idx_map, out);
    hipLaunchKernelGGL(k_gather, dim3(3072),     dim3(256), 0, stream,
                       z_p, m_p, logs_p, logs_q, lens, idx_map, out, partials);
    hipLaunchKernelGGL(k_final,  dim3(1),        dim3(256), 0, stream, partials, lens, out);
}